// Round 1
// baseline (2729.030 us; speedup 1.0000x reference)
//
#include <hip/hip_runtime.h>

// TIBlock: GCN branch (3× GLU-gated graph conv, adj_n applied as D@(A@(D@u))),
// CNN branch (3× GLU-gated conv1d k=7), 6× 1x1 QKV projections, dual cross
// attention (softmax then *NORM), mean-pool, reparam head.
// All fp32 (CDNA4 has no fp32 MFMA; vector-ALU GEMMs this round).

#define Bn 16
#define Nn 1024
#define C3n 192
static __device__ __constant__ float NORM_C = 0.07216878364870322f; // 1/sqrt(192)

// ------------------------------------------------------------------ GEMM
// C[M,N] = op(A)[M,K] @ op(B)[K,N] (+bias[n]) (+=C)
// !TA: A[m*lda+k]   TA: A[k*lda+m]
// !TB: B[k*ldb+n]   TB: B[n*ldb+k]
template<bool TA, bool TB, bool ACC, bool BIAS>
__global__ __launch_bounds__(256) void gemm_k(
    const float* __restrict__ A, long sA, int lda,
    const float* __restrict__ Bm, long sB, int ldb,
    const float* __restrict__ bias,
    float* __restrict__ C, long sC,
    int M, int N, int K)
{
  constexpr int TILE = 64, KS = 16;
  __shared__ float smA[TILE * (KS + 1)];
  __shared__ float smB[TILE * (KS + 1)];
  const int bz = blockIdx.z;
  A  += (long)bz * sA;
  Bm += (long)bz * sB;
  C  += (long)bz * sC;
  const int n0 = blockIdx.x * TILE, m0 = blockIdx.y * TILE;
  const int tid = threadIdx.x;
  const int tx = tid & 15, ty = tid >> 4;
  float acc[4][4] = {};

  for (int k0 = 0; k0 < K; k0 += KS) {
    if constexpr (TA) { // A stored [K,M]: m-fast coalesced, LDS [k][m]
      const int m = tid & 63, kq = tid >> 6;
#pragma unroll
      for (int i = 0; i < 4; ++i) {
        const int k = kq * 4 + i;
        smA[k * TILE + m] = A[(long)(k0 + k) * lda + (m0 + m)];
      }
    } else {            // A stored [M,K]: k-fast coalesced, LDS [m][k] padded
      const int kk = tid & 15, mq = tid >> 4;
#pragma unroll
      for (int i = 0; i < 4; ++i) {
        const int m = mq + 16 * i;
        smA[m * (KS + 1) + kk] = A[(long)(m0 + m) * lda + (k0 + kk)];
      }
    }
    if constexpr (!TB) { // B stored [K,N]: n-fast coalesced, LDS [k][n]
      const int n = tid & 63, kq = tid >> 6;
#pragma unroll
      for (int i = 0; i < 4; ++i) {
        const int k = kq * 4 + i;
        smB[k * TILE + n] = Bm[(long)(k0 + k) * ldb + (n0 + n)];
      }
    } else {             // B stored [N,K]: k-fast coalesced, LDS [n][k] padded
      const int kk = tid & 15, nq = tid >> 4;
#pragma unroll
      for (int i = 0; i < 4; ++i) {
        const int n = nq + 16 * i;
        smB[n * (KS + 1) + kk] = Bm[(long)(n0 + n) * ldb + (k0 + kk)];
      }
    }
    __syncthreads();
#pragma unroll
    for (int k = 0; k < KS; ++k) {
      float a[4], bv[4];
      if constexpr (TA) {
        const float4 t = *reinterpret_cast<const float4*>(&smA[k * TILE + ty * 4]);
        a[0] = t.x; a[1] = t.y; a[2] = t.z; a[3] = t.w;
      } else {
#pragma unroll
        for (int i = 0; i < 4; ++i) a[i] = smA[(ty * 4 + i) * (KS + 1) + k];
      }
      if constexpr (!TB) {
        const float4 t = *reinterpret_cast<const float4*>(&smB[k * TILE + tx * 4]);
        bv[0] = t.x; bv[1] = t.y; bv[2] = t.z; bv[3] = t.w;
      } else {
#pragma unroll
        for (int j = 0; j < 4; ++j) bv[j] = smB[(tx * 4 + j) * (KS + 1) + k];
      }
#pragma unroll
      for (int i = 0; i < 4; ++i)
#pragma unroll
        for (int j = 0; j < 4; ++j)
          acc[i][j] = fmaf(a[i], bv[j], acc[i][j]);
    }
    __syncthreads();
  }

#pragma unroll
  for (int i = 0; i < 4; ++i) {
    const int m = m0 + ty * 4 + i;
    float4 v;
    v.x = acc[i][0]; v.y = acc[i][1]; v.z = acc[i][2]; v.w = acc[i][3];
    float4* cp = reinterpret_cast<float4*>(&C[(long)m * N + n0 + tx * 4]);
    if constexpr (BIAS) {
      const float4 bb = *reinterpret_cast<const float4*>(&bias[n0 + tx * 4]);
      v.x += bb.x; v.y += bb.y; v.z += bb.z; v.w += bb.w;
    }
    if constexpr (ACC) {
      const float4 c0 = *cp;
      v.x += c0.x; v.y += c0.y; v.z += c0.z; v.w += c0.w;
    }
    *cp = v;
  }
}

// ------------------------------------------------------------------ GLU (GCN, split last dim)
__global__ void glu_bias_k(const float* __restrict__ z, const float* __restrict__ bias,
                           float* __restrict__ g, int half)
{
  const long i = (long)blockIdx.x * blockDim.x + threadIdx.x;
  const long total = (long)Bn * Nn * half;
  if (i >= total) return;
  const int h = (int)(i % half);
  const long row = i / half;
  const int ld = 2 * half;
  const float o  = z[row * ld + h] + bias[h];
  const float gt = z[row * ld + half + h] + bias[half + h];
  g[i] = o * (1.f / (1.f + __expf(-gt) * 0.f + expf(-gt))); // keep exact expf
}

// ------------------------------------------------------------------ transpose x [B,N,128] -> xc [B,128,N]
__global__ void transpose_k(const float* __restrict__ x, float* __restrict__ xc)
{
  __shared__ float t[32][33];
  const int b = blockIdx.z;
  const int n0 = blockIdx.x * 32, c0 = blockIdx.y * 32;
  const int tx = threadIdx.x, ty = threadIdx.y; // 32x8
#pragma unroll
  for (int i = 0; i < 32; i += 8)
    t[ty + i][tx] = x[((long)b * Nn + n0 + ty + i) * 128 + c0 + tx];
  __syncthreads();
#pragma unroll
  for (int i = 0; i < 32; i += 8)
    xc[((long)b * 128 + c0 + ty + i) * Nn + n0 + tx] = t[tx][ty + i];
}

// ------------------------------------------------------------------ conv1d k=7 pad=3 + channel GLU
// in [B,Ci,N] -> out [B,CoH,N];  w [2*CoH, Ci, 7]
__global__ __launch_bounds__(256) void conv_glu_k(
    const float* __restrict__ in, const float* __restrict__ w,
    const float* __restrict__ bias, float* __restrict__ out,
    int Ci, int CoH)
{
  const int n = blockIdx.x * 256 + threadIdx.x;
  const int h = blockIdx.y;
  const int b = blockIdx.z;
  const float* inb = in + (long)b * Ci * Nn;
  const float* wo = w + (long)h * Ci * 7;
  const float* wg = w + (long)(h + CoH) * Ci * 7;
  float acco = bias[h], accg = bias[h + CoH];
  for (int ci = 0; ci < Ci; ++ci) {
    const float* row = inb + (long)ci * Nn;
#pragma unroll
    for (int t = 0; t < 7; ++t) {
      const int idx = n + t - 3;
      const float v = (idx >= 0 && idx < Nn) ? row[idx] : 0.f;
      acco = fmaf(wo[ci * 7 + t], v, acco);
      accg = fmaf(wg[ci * 7 + t], v, accg);
    }
  }
  out[((long)b * CoH + h) * Nn + n] = acco * (1.f / (1.f + expf(-accg)));
}

// ------------------------------------------------------------------ row softmax, scaled AFTER softmax
__global__ __launch_bounds__(256) void softmax_scale_k(float* __restrict__ S)
{
  const int row = blockIdx.x, b = blockIdx.y;
  float* p = S + ((long)b * Nn + row) * Nn;
  const int tid = threadIdx.x; // 256 threads x float4 = 1024
  float4 v = reinterpret_cast<float4*>(p)[tid];
  float m = fmaxf(fmaxf(v.x, v.y), fmaxf(v.z, v.w));
#pragma unroll
  for (int off = 32; off; off >>= 1) m = fmaxf(m, __shfl_xor(m, off));
  __shared__ float redm[4];
  if ((tid & 63) == 0) redm[tid >> 6] = m;
  __syncthreads();
  m = fmaxf(fmaxf(redm[0], redm[1]), fmaxf(redm[2], redm[3]));
  const float e0 = expf(v.x - m), e1 = expf(v.y - m), e2 = expf(v.z - m), e3 = expf(v.w - m);
  float s = e0 + e1 + e2 + e3;
#pragma unroll
  for (int off = 32; off; off >>= 1) s += __shfl_xor(s, off);
  __shared__ float reds[4];
  if ((tid & 63) == 0) reds[tid >> 6] = s;
  __syncthreads();
  s = reds[0] + reds[1] + reds[2] + reds[3];
  const float inv = NORM_C / s;
  float4 o; o.x = e0 * inv; o.y = e1 * inv; o.z = e2 * inv; o.w = e3 * inv;
  reinterpret_cast<float4*>(p)[tid] = o;
}

// ------------------------------------------------------------------ mean pool over N
__global__ void pool_k(const float* __restrict__ feat, float* __restrict__ pooled)
{
  const int b = blockIdx.x, c = threadIdx.x; // 192 threads
  float s = 0.f;
  for (int n = 0; n < Nn; ++n) s += feat[((long)b * Nn + n) * C3n + c];
  pooled[b * C3n + c] = s * (1.f / Nn);
}

// ------------------------------------------------------------------ head: l1/l2 + reparam
__global__ void head_k(const float* __restrict__ pooled,
                       const float* __restrict__ l1w, const float* __restrict__ l1b,
                       const float* __restrict__ l2w, const float* __restrict__ l2b,
                       const float* __restrict__ eps, float* __restrict__ out)
{
  const int b = blockIdx.x, o = threadIdx.x; // 192 threads
  __shared__ float sp[C3n];
  sp[o] = pooled[b * C3n + o];
  __syncthreads();
  float d1 = l1b[o], d2 = l2b[o];
  for (int c = 0; c < C3n; ++c) {
    d1 = fmaf(sp[c], l1w[o * C3n + c], d1);
    d2 = fmaf(sp[c], l2w[o * C3n + c], d2);
  }
  const float o1 = fmaxf(d1, 0.f);
  const float o2 = fmaxf(d2, 0.f);
  const float sd = expf(0.5f * o2);
  out[b * C3n + o] = eps[b * C3n + o] * sd + o1;            // out0
  out[Bn * C3n + b * C3n + o] = o1;                          // out1
  out[2 * Bn * C3n + b * C3n + o] = o2;                      // out2
}

// ------------------------------------------------------------------ launch
extern "C" void kernel_launch(void* const* d_in, const int* in_sizes, int n_in,
                              void* d_out, int out_size, void* d_ws, size_t ws_size,
                              hipStream_t stream)
{
  const float* x    = (const float*)d_in[0];
  const float* adjm = (const float*)d_in[1];
  const float* deg  = (const float*)d_in[2];
  const float* eps  = (const float*)d_in[3];
  const float* g1w  = (const float*)d_in[4];
  const float* g1b  = (const float*)d_in[5];
  const float* g2w  = (const float*)d_in[6];
  const float* g2b  = (const float*)d_in[7];
  const float* g3w  = (const float*)d_in[8];
  const float* g3b  = (const float*)d_in[9];
  const float* c1w  = (const float*)d_in[10];
  const float* c1b  = (const float*)d_in[11];
  const float* c2w  = (const float*)d_in[12];
  const float* c2b  = (const float*)d_in[13];
  const float* c3w  = (const float*)d_in[14];
  const float* c3b  = (const float*)d_in[15];
  const float* srqw = (const float*)d_in[16];
  const float* srqb = (const float*)d_in[17];
  const float* srkw = (const float*)d_in[18];
  const float* srkb = (const float*)d_in[19];
  const float* srvw = (const float*)d_in[20];
  const float* srvb = (const float*)d_in[21];
  const float* drqw = (const float*)d_in[22];
  const float* drqb = (const float*)d_in[23];
  const float* drkw = (const float*)d_in[24];
  const float* drkb = (const float*)d_in[25];
  const float* drvw = (const float*)d_in[26];
  const float* drvb = (const float*)d_in[27];
  const float* l1w  = (const float*)d_in[28];
  const float* l1b  = (const float*)d_in[29];
  const float* l2w  = (const float*)d_in[30];
  const float* l2b  = (const float*)d_in[31];
  float* out = (float*)d_out;
  char* ws = (char*)d_ws;

  // workspace layout (bytes); S (64MB) overlaps tmp1/tmp2/xc/c1/c2 (dead by attention)
  constexpr long SZ_TMP = (long)Bn * Nn * 384 * 4;        // 24MB
  constexpr long O_TMP1 = 0;
  constexpr long O_TMP2 = SZ_TMP;
  constexpr long O_XC   = 2 * SZ_TMP;                     // 48MB
  constexpr long O_C1   = O_XC + (long)Bn * 128 * Nn * 4; // +8MB
  constexpr long O_C2   = O_C1 + (long)Bn * 64 * Nn * 4;  // +4MB
  constexpr long O_G1   = O_C2 + (long)Bn * 128 * Nn * 4; // +8MB -> 68MB
  constexpr long O_G2   = O_G1 + (long)Bn * Nn * 64 * 4;
  constexpr long O_G3   = O_G2 + (long)Bn * Nn * 128 * 4;
  constexpr long O_CNN  = O_G3 + (long)Bn * Nn * 192 * 4;
  constexpr long SZ_QKV = (long)Bn * Nn * 192 * 4;        // 12MB
  constexpr long O_SRQ  = O_CNN + SZ_QKV;
  constexpr long O_SRK  = O_SRQ + SZ_QKV;
  constexpr long O_SRV  = O_SRK + SZ_QKV;
  constexpr long O_DRQ  = O_SRV + SZ_QKV;
  constexpr long O_DRK  = O_DRQ + SZ_QKV;
  constexpr long O_DRV  = O_DRK + SZ_QKV;
  constexpr long O_FEAT = O_DRV + SZ_QKV;
  constexpr long O_POOL = O_FEAT + SZ_QKV;
  constexpr long O_S    = 0; // overlaps [0, 64MB) < O_G1

  float* tmp1 = (float*)(ws + O_TMP1);
  float* tmp2 = (float*)(ws + O_TMP2);
  float* xc   = (float*)(ws + O_XC);
  float* c1   = (float*)(ws + O_C1);
  float* c2   = (float*)(ws + O_C2);
  float* G1   = (float*)(ws + O_G1);
  float* G2   = (float*)(ws + O_G2);
  float* G3   = (float*)(ws + O_G3);
  float* CNN  = (float*)(ws + O_CNN);
  float* SRQ  = (float*)(ws + O_SRQ);
  float* SRK  = (float*)(ws + O_SRK);
  float* SRV  = (float*)(ws + O_SRV);
  float* DRQ  = (float*)(ws + O_DRQ);
  float* DRK  = (float*)(ws + O_DRK);
  float* DRV  = (float*)(ws + O_DRV);
  float* FEAT = (float*)(ws + O_FEAT);
  float* POOL = (float*)(ws + O_POOL);
  float* S    = (float*)(ws + O_S);

  const long sNN = (long)Nn * Nn;

#define GEMM(TA,TB,ACC,BIAS, Ap,sAp,ldap, Bp,sBp,ldbp, biasp, Cp,sCp, M,Np,Kp) \
  gemm_k<TA,TB,ACC,BIAS><<<dim3((Np)/64,(M)/64,Bn), 256, 0, stream>>>( \
      Ap, sAp, ldap, Bp, sBp, ldbp, biasp, Cp, sCp, M, Np, Kp)

  // ---------------- GCN branch: g = GLU(D@(A@(D@(in@W))) + b) ----------------
  // layer 1: in=x [B,N,128], W1 [128,128]
  GEMM(false,false,false,false, x,(long)Nn*128,128, g1w,0,128, nullptr, tmp1,(long)Nn*128, Nn,128,128);
  GEMM(false,false,false,false, deg,sNN,Nn, tmp1,(long)Nn*128,128, nullptr, tmp2,(long)Nn*128, Nn,128,Nn);
  GEMM(false,false,false,false, adjm,sNN,Nn, tmp2,(long)Nn*128,128, nullptr, tmp1,(long)Nn*128, Nn,128,Nn);
  GEMM(false,false,false,false, deg,sNN,Nn, tmp1,(long)Nn*128,128, nullptr, tmp2,(long)Nn*128, Nn,128,Nn);
  glu_bias_k<<<(Bn*Nn*64)/256, 256, 0, stream>>>(tmp2, g1b, G1, 64);
  // layer 2: in=G1 [B,N,64], W2 [64,256]
  GEMM(false,false,false,false, G1,(long)Nn*64,64, g2w,0,256, nullptr, tmp1,(long)Nn*256, Nn,256,64);
  GEMM(false,false,false,false, deg,sNN,Nn, tmp1,(long)Nn*256,256, nullptr, tmp2,(long)Nn*256, Nn,256,Nn);
  GEMM(false,false,false,false, adjm,sNN,Nn, tmp2,(long)Nn*256,256, nullptr, tmp1,(long)Nn*256, Nn,256,Nn);
  GEMM(false,false,false,false, deg,sNN,Nn, tmp1,(long)Nn*256,256, nullptr, tmp2,(long)Nn*256, Nn,256,Nn);
  glu_bias_k<<<(Bn*Nn*128)/256, 256, 0, stream>>>(tmp2, g2b, G2, 128);
  // layer 3: in=G2 [B,N,128], W3 [128,384]
  GEMM(false,false,false,false, G2,(long)Nn*128,128, g3w,0,384, nullptr, tmp1,(long)Nn*384, Nn,384,128);
  GEMM(false,false,false,false, deg,sNN,Nn, tmp1,(long)Nn*384,384, nullptr, tmp2,(long)Nn*384, Nn,384,Nn);
  GEMM(false,false,false,false, adjm,sNN,Nn, tmp2,(long)Nn*384,384, nullptr, tmp1,(long)Nn*384, Nn,384,Nn);
  GEMM(false,false,false,false, deg,sNN,Nn, tmp1,(long)Nn*384,384, nullptr, tmp2,(long)Nn*384, Nn,384,Nn);
  glu_bias_k<<<(Bn*Nn*192)/256, 256, 0, stream>>>(tmp2, g3b, G3, 192);  // G3 = [B,N,192]

  // ---------------- CNN branch ----------------
  transpose_k<<<dim3(Nn/32, 128/32, Bn), dim3(32, 8), 0, stream>>>(x, xc);
  conv_glu_k<<<dim3(Nn/256, 64,  Bn), 256, 0, stream>>>(xc, c1w, c1b, c1, 128, 64);
  conv_glu_k<<<dim3(Nn/256, 128, Bn), 256, 0, stream>>>(c1, c2w, c2b, c2, 64, 128);
  conv_glu_k<<<dim3(Nn/256, 192, Bn), 256, 0, stream>>>(c2, c3w, c3b, CNN, 128, 192); // CNN = [B,192,N]

  // ---------------- QKV projections (all row-major [B,N,192] outputs) ----------------
  GEMM(true ,true ,false,true , CNN,(long)192*Nn,Nn, srqw,0,192, srqb, SRQ,(long)Nn*192, Nn,192,192);
  GEMM(true ,true ,false,true , CNN,(long)192*Nn,Nn, srkw,0,192, srkb, SRK,(long)Nn*192, Nn,192,192);
  GEMM(true ,true ,false,true , CNN,(long)192*Nn,Nn, srvw,0,192, srvb, SRV,(long)Nn*192, Nn,192,192);
  GEMM(false,true ,false,true , G3,(long)Nn*192,192, drqw,0,192, drqb, DRQ,(long)Nn*192, Nn,192,192);
  GEMM(false,true ,false,true , G3,(long)Nn*192,192, drkw,0,192, drkb, DRK,(long)Nn*192, Nn,192,192);
  GEMM(false,true ,false,true , G3,(long)Nn*192,192, drvw,0,192, drvb, DRV,(long)Nn*192, Nn,192,192);

  // ---------------- attention SR: softmax(SRQ·DRK)·NORM @ SRV ----------------
  GEMM(false,true ,false,false, SRQ,(long)Nn*192,192, DRK,(long)Nn*192,192, nullptr, S,sNN, Nn,Nn,192);
  softmax_scale_k<<<dim3(Nn, Bn), 256, 0, stream>>>(S);
  GEMM(false,false,false,false, S,sNN,Nn, SRV,(long)Nn*192,192, nullptr, FEAT,(long)Nn*192, Nn,192,Nn);
  // ---------------- attention DR: softmax(DRQ·SRK)·NORM @ DRV (accumulate) ----------------
  GEMM(false,true ,false,false, DRQ,(long)Nn*192,192, SRK,(long)Nn*192,192, nullptr, S,sNN, Nn,Nn,192);
  softmax_scale_k<<<dim3(Nn, Bn), 256, 0, stream>>>(S);
  GEMM(false,false,true ,false, S,sNN,Nn, DRV,(long)Nn*192,192, nullptr, FEAT,(long)Nn*192, Nn,192,Nn);

  // ---------------- pool + head ----------------
  pool_k<<<Bn, C3n, 0, stream>>>(FEAT, POOL);
  head_k<<<Bn, C3n, 0, stream>>>(POOL, l1w, l1b, l2w, l2b, eps, out);

#undef GEMM
}